// Round 5
// baseline (419.185 us; speedup 1.0000x reference)
//
#include <hip/hip_runtime.h>
#include <hip/hip_bf16.h>

#define N_NODES 8192
#define N_EDGES 262144

typedef __attribute__((ext_vector_type(8))) short short8v;
typedef __attribute__((ext_vector_type(4))) float float4v;

static __device__ __forceinline__ unsigned short f2bf(float f) {
    unsigned u = __float_as_uint(f);
    unsigned r = (u + 0x7FFF + ((u >> 16) & 1)) >> 16;   // RNE, finite values
    return (unsigned short)r;
}
static __device__ __forceinline__ float bf2f(unsigned short h) {
    return __uint_as_float(((unsigned)h) << 16);
}

// ---------------- fused: edge histogram + fp32->bf16 casts (independent, input-only) ----------------

__global__ __launch_bounds__(256) void hist_prep_kernel(const int* __restrict__ dst, int* __restrict__ deg,
                                                        const float* __restrict__ X, const float* __restrict__ W1,
                                                        const float* __restrict__ W2, const float* __restrict__ W3,
                                                        unsigned short* __restrict__ Xb,
                                                        unsigned short* __restrict__ W1b,
                                                        unsigned short* __restrict__ W23b) {
    int b = blockIdx.x;
    if (b < 1024) {
        int e = b * 256 + threadIdx.x;   // E == 1024*256 exactly
        atomicAdd(&deg[dst[e]], 1);
        return;
    }
    int i4 = ((b - 1024) * 256 + threadIdx.x) * 4;
    const float* srcp;
    unsigned short* dstp;
    int off;
    if (i4 < 4194304)      { srcp = X;  dstp = Xb;           off = i4; }
    else if (i4 < 4325376) { srcp = W1; dstp = W1b;          off = i4 - 4194304; }
    else if (i4 < 4341760) { srcp = W2; dstp = W23b;         off = i4 - 4325376; }
    else                   { srcp = W3; dstp = W23b + 16384; off = i4 - 4341760; }
    float4 v = *(const float4*)&srcp[off];
    ushort4 o = {f2bf(v.x), f2bf(v.y), f2bf(v.z), f2bf(v.w)};
    *(ushort4*)&dstp[off] = o;
}

// ---------------- exclusive scan; also initializes cur = offs for the scatter ----------------

__global__ __launch_bounds__(1024) void scan_kernel(const int* __restrict__ deg, int* __restrict__ offs,
                                                    int* __restrict__ cur) {
    __shared__ int sums[1024];
    int t = threadIdx.x;
    int v[8];
    int s = 0;
#pragma unroll
    for (int i = 0; i < 8; i++) { v[i] = deg[t * 8 + i]; s += v[i]; }
    sums[t] = s;
    __syncthreads();
    for (int off = 1; off < 1024; off <<= 1) {
        int x = (t >= off) ? sums[t - off] : 0;
        __syncthreads();
        sums[t] += x;
        __syncthreads();
    }
    int ex = (t == 0) ? 0 : sums[t - 1];
#pragma unroll
    for (int i = 0; i < 8; i++) { offs[t * 8 + i] = ex; cur[t * 8 + i] = ex; ex += v[i]; }
    if (t == 1023) offs[N_NODES] = ex;
}

__global__ __launch_bounds__(256) void scatter_kernel(const int* __restrict__ src, const int* __restrict__ dst,
                                                      int* __restrict__ cur, int* __restrict__ csr) {
    int e = blockIdx.x * 256 + threadIdx.x;
    int d = dst[e];
    int p = atomicAdd(&cur[d], 1);
    csr[p] = src[e];
}

// ---------------- MFMA GEMM: C[M,N] = A[M,K] @ B[N,K]^T, all row-major bf16 ----------------
// Direct global fragment loads: A[m=lane&15][k=(lane>>4)*8+j]; C/D: col=lane&15, row=(lane>>4)*4+reg.
// Block = 4 waves; WN waves along N, 4/WN along M. MI=2 -> 512 blocks (2 blocks/CU) for latency hiding.

template <int MI, int NJ, int WN>
__global__ __launch_bounds__(256) void gemm_nt_mfma(const unsigned short* __restrict__ A,
                                                    const unsigned short* __restrict__ B,
                                                    unsigned short* __restrict__ C,
                                                    int N, int K) {
    constexpr int MW = 4 / WN;
    const int tid = threadIdx.x;
    const int lane = tid & 63;
    const int w = tid >> 6;
    const int r = lane & 15, q = lane >> 4;
    const int m0 = blockIdx.x * (MI * 16 * MW) + (w / WN) * (MI * 16);
    const int n0 = blockIdx.y * (NJ * 16 * WN) + (w % WN) * (NJ * 16);
    float4v acc[MI][NJ] = {};
    for (int k = 0; k < K; k += 32) {
        short8v a[MI], b[NJ];
#pragma unroll
        for (int i = 0; i < MI; i++)
            a[i] = *(const short8v*)&A[(size_t)(m0 + i * 16 + r) * K + k + q * 8];
#pragma unroll
        for (int j = 0; j < NJ; j++)
            b[j] = *(const short8v*)&B[(size_t)(n0 + j * 16 + r) * K + k + q * 8];
#pragma unroll
        for (int i = 0; i < MI; i++)
#pragma unroll
            for (int j = 0; j < NJ; j++)
                acc[i][j] = __builtin_amdgcn_mfma_f32_16x16x32_bf16(a[i], b[j], acc[i][j], 0, 0, 0);
    }
#pragma unroll
    for (int i = 0; i < MI; i++)
#pragma unroll
        for (int j = 0; j < NJ; j++) {
            int col = n0 + j * 16 + r;
#pragma unroll
            for (int t = 0; t < 4; t++) {
                int row = m0 + i * 16 + q * 4 + t;
                C[(size_t)row * N + col] = f2bf(acc[i][j][t]);
            }
        }
}

// ---------------- Aggregation (CSR gather-sum) over bf16 Y1 [N,256], + bias + relu -> bf16 hidden ----------------

__global__ __launch_bounds__(256) void agg_relu_kernel(const unsigned short* __restrict__ Yb,
                                                       const int* __restrict__ offs,
                                                       const int* __restrict__ csr, const float* __restrict__ bias,
                                                       unsigned short* __restrict__ out) {
    int node = blockIdx.x * 4 + (threadIdx.x >> 6);
    int lane = threadIdx.x & 63;
    int s = offs[node], e = offs[node + 1];
    float4 acc0 = {0.f, 0.f, 0.f, 0.f}, acc1 = {0.f, 0.f, 0.f, 0.f};
    int i = s;
    for (; i + 3 < e; i += 4) {
        int u0 = csr[i], u1 = csr[i + 1], u2 = csr[i + 2], u3 = csr[i + 3];
        ushort4 v0 = *(const ushort4*)&Yb[(size_t)u0 * 256 + lane * 4];
        ushort4 v1 = *(const ushort4*)&Yb[(size_t)u1 * 256 + lane * 4];
        ushort4 v2 = *(const ushort4*)&Yb[(size_t)u2 * 256 + lane * 4];
        ushort4 v3 = *(const ushort4*)&Yb[(size_t)u3 * 256 + lane * 4];
        acc0.x += bf2f(v0.x) + bf2f(v1.x); acc1.x += bf2f(v2.x) + bf2f(v3.x);
        acc0.y += bf2f(v0.y) + bf2f(v1.y); acc1.y += bf2f(v2.y) + bf2f(v3.y);
        acc0.z += bf2f(v0.z) + bf2f(v1.z); acc1.z += bf2f(v2.z) + bf2f(v3.z);
        acc0.w += bf2f(v0.w) + bf2f(v1.w); acc1.w += bf2f(v2.w) + bf2f(v3.w);
    }
    for (; i < e; i++) {
        int u = csr[i];
        ushort4 v = *(const ushort4*)&Yb[(size_t)u * 256 + lane * 4];
        acc0.x += bf2f(v.x); acc0.y += bf2f(v.y); acc0.z += bf2f(v.z); acc0.w += bf2f(v.w);
    }
    float4 b = *(const float4*)&bias[lane * 4];
    ushort4 o;
    o.x = f2bf(fmaxf(acc0.x + acc1.x + b.x, 0.f));
    o.y = f2bf(fmaxf(acc0.y + acc1.y + b.y, 0.f));
    o.z = f2bf(fmaxf(acc0.z + acc1.z + b.z, 0.f));
    o.w = f2bf(fmaxf(acc0.w + acc1.w + b.w, 0.f));
    *(ushort4*)&out[(size_t)node * 256 + lane * 4] = o;
}

// ---------------- Aggregation over bf16 Z [N,128] -> mu/logvar fp32 (+bias) and bf16 zb [N,64] ----------------

__global__ __launch_bounds__(256) void agg_split_kernel(const unsigned short* __restrict__ Zb,
                                                        const int* __restrict__ offs,
                                                        const int* __restrict__ csr, const float* __restrict__ b2,
                                                        const float* __restrict__ b3, float* __restrict__ mu,
                                                        float* __restrict__ lv, unsigned short* __restrict__ zb) {
    int node = blockIdx.x * 4 + (threadIdx.x >> 6);
    int lane = threadIdx.x & 63;
    int s = offs[node], e = offs[node + 1];
    float2 acc0 = {0.f, 0.f}, acc1 = {0.f, 0.f};
    int i = s;
    for (; i + 3 < e; i += 4) {
        int u0 = csr[i], u1 = csr[i + 1], u2 = csr[i + 2], u3 = csr[i + 3];
        ushort2 v0 = *(const ushort2*)&Zb[(size_t)u0 * 128 + lane * 2];
        ushort2 v1 = *(const ushort2*)&Zb[(size_t)u1 * 128 + lane * 2];
        ushort2 v2 = *(const ushort2*)&Zb[(size_t)u2 * 128 + lane * 2];
        ushort2 v3 = *(const ushort2*)&Zb[(size_t)u3 * 128 + lane * 2];
        acc0.x += bf2f(v0.x) + bf2f(v1.x); acc1.x += bf2f(v2.x) + bf2f(v3.x);
        acc0.y += bf2f(v0.y) + bf2f(v1.y); acc1.y += bf2f(v2.y) + bf2f(v3.y);
    }
    for (; i < e; i++) {
        int u = csr[i];
        ushort2 v = *(const ushort2*)&Zb[(size_t)u * 128 + lane * 2];
        acc0.x += bf2f(v.x); acc0.y += bf2f(v.y);
    }
    float2 acc = {acc0.x + acc1.x, acc0.y + acc1.y};
    int col = lane * 2;
    if (col < 64) {
        acc.x += b2[col]; acc.y += b2[col + 1];
        *(float2*)&mu[(size_t)node * 64 + col] = acc;
        ushort2 q = {f2bf(acc.x), f2bf(acc.y)};
        *(ushort2*)&zb[(size_t)node * 64 + col] = q;
    } else {
        col -= 64;
        acc.x += b3[col]; acc.y += b3[col + 1];
        *(float2*)&lv[(size_t)node * 64 + col] = acc;
    }
}

// ---------------- adj = sigmoid(z z^T) via bf16 MFMA; zb = [8192, 64] bf16 ----------------

__global__ __launch_bounds__(256) void adj_mfma_kernel(const unsigned short* __restrict__ zb,
                                                       float* __restrict__ out) {
    const int tid = threadIdx.x;
    const int lane = tid & 63;
    const int wid = tid >> 6;
    const int waveM = wid >> 1, waveN = wid & 1;
    const int m_base = blockIdx.x * 128 + waveM * 64;
    const int n_base = blockIdx.y * 128 + waveN * 64;
    const int r = lane & 15;
    const int q = lane >> 4;

    short8v a[4][2], b[4][2];
#pragma unroll
    for (int i = 0; i < 4; i++)
#pragma unroll
        for (int s = 0; s < 2; s++) {
            a[i][s] = *(const short8v*)&zb[(size_t)(m_base + i * 16 + r) * 64 + s * 32 + q * 8];
            b[i][s] = *(const short8v*)&zb[(size_t)(n_base + i * 16 + r) * 64 + s * 32 + q * 8];
        }

    float4v acc[4][4] = {};
#pragma unroll
    for (int s = 0; s < 2; s++)
#pragma unroll
        for (int i = 0; i < 4; i++)
#pragma unroll
            for (int j = 0; j < 4; j++)
                acc[i][j] = __builtin_amdgcn_mfma_f32_16x16x32_bf16(a[i][s], b[j][s], acc[i][j], 0, 0, 0);

#pragma unroll
    for (int i = 0; i < 4; i++)
#pragma unroll
        for (int j = 0; j < 4; j++) {
            int col = n_base + j * 16 + r;
#pragma unroll
            for (int t = 0; t < 4; t++) {
                int row = m_base + i * 16 + q * 4 + t;
                float v = 1.0f / (1.0f + __expf(-acc[i][j][t]));
                __builtin_nontemporal_store(v, &out[(size_t)row * N_NODES + col]);
            }
        }
}

// ---------------- launch ----------------

extern "C" void kernel_launch(void* const* d_in, const int* in_sizes, int n_in,
                              void* d_out, int out_size, void* d_ws, size_t ws_size,
                              hipStream_t stream) {
    const float* X   = (const float*)d_in[0];
    const int*   src = (const int*)d_in[1];
    const int*   dst = (const int*)d_in[2];
    const float* W1  = (const float*)d_in[3];
    const float* b1  = (const float*)d_in[4];
    const float* W2  = (const float*)d_in[5];
    const float* b2  = (const float*)d_in[6];
    const float* W3  = (const float*)d_in[7];
    const float* b3  = (const float*)d_in[8];

    float* out    = (float*)d_out;
    float* adj    = out;                              // [8192*8192]
    float* mu_out = out + (size_t)N_NODES * N_NODES;  // [8192*64]
    float* lv_out = mu_out + (size_t)N_NODES * 64;    // [8192*64]

    // Workspace allocator: 1 KiB-aligned carve-outs (R2 lesson: no hand arithmetic).
    char* ws = (char*)d_ws;
    size_t off = 0;
    auto alloc = [&](size_t bytes) -> void* {
        void* p = ws + off;
        off += (bytes + 1023) & ~(size_t)1023;
        return p;
    };
    int* deg            = (int*)alloc(N_NODES * 4);
    int* cur            = (int*)alloc(N_NODES * 4);
    int* offs           = (int*)alloc((N_NODES + 1) * 4);
    int* csr            = (int*)alloc(N_EDGES * 4);
    unsigned short* Xb  = (unsigned short*)alloc((size_t)N_NODES * 512 * 2);
    unsigned short* W1b = (unsigned short*)alloc(256 * 512 * 2);
    unsigned short* W23b= (unsigned short*)alloc(128 * 256 * 2);
    unsigned short* Y1b = (unsigned short*)alloc((size_t)N_NODES * 256 * 2);
    unsigned short* Hb  = (unsigned short*)alloc((size_t)N_NODES * 256 * 2);
    unsigned short* Zb  = (unsigned short*)alloc((size_t)N_NODES * 128 * 2);
    unsigned short* zb  = (unsigned short*)alloc((size_t)N_NODES * 64 * 2);

    hipMemsetAsync(deg, 0, N_NODES * sizeof(int), stream);
    // hist (1024 blocks) + bf16 casts (4256 blocks) fused
    hist_prep_kernel<<<5280, 256, 0, stream>>>(dst, deg, X, W1, W2, W3, Xb, W1b, W23b);
    scan_kernel<<<1, 1024, 0, stream>>>(deg, offs, cur);           // also cur = offs
    scatter_kernel<<<N_EDGES / 256, 256, 0, stream>>>(src, dst, cur, csr);

    // Y1b = bf16(Xb @ W1b^T) : [8192,512]x[256,512]^T -> [8192,256]
    gemm_nt_mfma<2, 2, 4><<<dim3(256, 2), 256, 0, stream>>>(Xb, W1b, Y1b, 256, 512);
    // Hb = bf16(relu(agg(Y1b) + b1))
    agg_relu_kernel<<<N_NODES / 4, 256, 0, stream>>>(Y1b, offs, csr, b1, Hb);
    // Zb = bf16(Hb @ W23b^T) : [8192,256]x[128,256]^T -> [8192,128]
    gemm_nt_mfma<2, 1, 4><<<dim3(256, 2), 256, 0, stream>>>(Hb, W23b, Zb, 128, 256);
    // mu/logvar = agg(Zb) + b2/b3 (split); zb = bf16(mu)
    agg_split_kernel<<<N_NODES / 4, 256, 0, stream>>>(Zb, offs, csr, b2, b3, mu_out, lv_out, zb);
    // adj = sigmoid(zb @ zb^T) via MFMA, nontemporal stores
    adj_mfma_kernel<<<dim3(64, 64), 256, 0, stream>>>(zb, adj);
}

// Round 6
// 389.010 us; speedup vs baseline: 1.0776x; 1.0776x over previous
//
#include <hip/hip_runtime.h>
#include <hip/hip_bf16.h>

#define N_NODES 8192
#define N_EDGES 262144

typedef __attribute__((ext_vector_type(8))) short short8v;
typedef __attribute__((ext_vector_type(4))) float float4v;

static __device__ __forceinline__ unsigned short f2bf(float f) {
    unsigned u = __float_as_uint(f);
    unsigned r = (u + 0x7FFF + ((u >> 16) & 1)) >> 16;   // RNE, finite values
    return (unsigned short)r;
}
static __device__ __forceinline__ float bf2f(unsigned short h) {
    return __uint_as_float(((unsigned)h) << 16);
}

// ---------------- fused: edge histogram + fp32->bf16 casts (independent, input-only) ----------------

__global__ __launch_bounds__(256) void hist_prep_kernel(const int* __restrict__ dst, int* __restrict__ deg,
                                                        const float* __restrict__ X, const float* __restrict__ W1,
                                                        const float* __restrict__ W2, const float* __restrict__ W3,
                                                        unsigned short* __restrict__ Xb,
                                                        unsigned short* __restrict__ W1b,
                                                        unsigned short* __restrict__ W23b) {
    int b = blockIdx.x;
    if (b < 1024) {
        int e = b * 256 + threadIdx.x;   // E == 1024*256 exactly
        atomicAdd(&deg[dst[e]], 1);
        return;
    }
    int i4 = ((b - 1024) * 256 + threadIdx.x) * 4;
    const float* srcp;
    unsigned short* dstp;
    int off;
    if (i4 < 4194304)      { srcp = X;  dstp = Xb;           off = i4; }
    else if (i4 < 4325376) { srcp = W1; dstp = W1b;          off = i4 - 4194304; }
    else if (i4 < 4341760) { srcp = W2; dstp = W23b;         off = i4 - 4325376; }
    else                   { srcp = W3; dstp = W23b + 16384; off = i4 - 4341760; }
    float4 v = *(const float4*)&srcp[off];
    ushort4 o = {f2bf(v.x), f2bf(v.y), f2bf(v.z), f2bf(v.w)};
    *(ushort4*)&dstp[off] = o;
}

// ---------------- exclusive scan; also initializes cur = offs for the scatter ----------------

__global__ __launch_bounds__(1024) void scan_kernel(const int* __restrict__ deg, int* __restrict__ offs,
                                                    int* __restrict__ cur) {
    __shared__ int sums[1024];
    int t = threadIdx.x;
    int v[8];
    int s = 0;
#pragma unroll
    for (int i = 0; i < 8; i++) { v[i] = deg[t * 8 + i]; s += v[i]; }
    sums[t] = s;
    __syncthreads();
    for (int off = 1; off < 1024; off <<= 1) {
        int x = (t >= off) ? sums[t - off] : 0;
        __syncthreads();
        sums[t] += x;
        __syncthreads();
    }
    int ex = (t == 0) ? 0 : sums[t - 1];
#pragma unroll
    for (int i = 0; i < 8; i++) { offs[t * 8 + i] = ex; cur[t * 8 + i] = ex; ex += v[i]; }
    if (t == 1023) offs[N_NODES] = ex;
}

__global__ __launch_bounds__(256) void scatter_kernel(const int* __restrict__ src, const int* __restrict__ dst,
                                                      int* __restrict__ cur, int* __restrict__ csr) {
    int e = blockIdx.x * 256 + threadIdx.x;
    int d = dst[e];
    int p = atomicAdd(&cur[d], 1);
    csr[p] = src[e];
}

// ---------------- MFMA GEMM: C[M,N] = A[M,K] @ B[N,K]^T, all row-major bf16 ----------------
// Direct global fragment loads: A[m=lane&15][k=(lane>>4)*8+j]; C/D: col=lane&15, row=(lane>>4)*4+reg.

template <int MI, int NJ, int WN>
__global__ __launch_bounds__(256) void gemm_nt_mfma(const unsigned short* __restrict__ A,
                                                    const unsigned short* __restrict__ B,
                                                    unsigned short* __restrict__ C,
                                                    int N, int K) {
    constexpr int MW = 4 / WN;
    const int tid = threadIdx.x;
    const int lane = tid & 63;
    const int w = tid >> 6;
    const int r = lane & 15, q = lane >> 4;
    const int m0 = blockIdx.x * (MI * 16 * MW) + (w / WN) * (MI * 16);
    const int n0 = blockIdx.y * (NJ * 16 * WN) + (w % WN) * (NJ * 16);
    float4v acc[MI][NJ] = {};
    for (int k = 0; k < K; k += 32) {
        short8v a[MI], b[NJ];
#pragma unroll
        for (int i = 0; i < MI; i++)
            a[i] = *(const short8v*)&A[(size_t)(m0 + i * 16 + r) * K + k + q * 8];
#pragma unroll
        for (int j = 0; j < NJ; j++)
            b[j] = *(const short8v*)&B[(size_t)(n0 + j * 16 + r) * K + k + q * 8];
#pragma unroll
        for (int i = 0; i < MI; i++)
#pragma unroll
            for (int j = 0; j < NJ; j++)
                acc[i][j] = __builtin_amdgcn_mfma_f32_16x16x32_bf16(a[i], b[j], acc[i][j], 0, 0, 0);
    }
#pragma unroll
    for (int i = 0; i < MI; i++)
#pragma unroll
        for (int j = 0; j < NJ; j++) {
            int col = n0 + j * 16 + r;
#pragma unroll
            for (int t = 0; t < 4; t++) {
                int row = m0 + i * 16 + q * 4 + t;
                C[(size_t)row * N + col] = f2bf(acc[i][j][t]);
            }
        }
}

// ---------------- Aggregation (CSR gather-sum) over bf16 Y1 [N,256], + bias + relu -> bf16 hidden ----------------

__global__ __launch_bounds__(256) void agg_relu_kernel(const unsigned short* __restrict__ Yb,
                                                       const int* __restrict__ offs,
                                                       const int* __restrict__ csr, const float* __restrict__ bias,
                                                       unsigned short* __restrict__ out) {
    int node = blockIdx.x * 4 + (threadIdx.x >> 6);
    int lane = threadIdx.x & 63;
    int s = offs[node], e = offs[node + 1];
    float4 acc0 = {0.f, 0.f, 0.f, 0.f}, acc1 = {0.f, 0.f, 0.f, 0.f};
    int i = s;
    for (; i + 3 < e; i += 4) {
        int u0 = csr[i], u1 = csr[i + 1], u2 = csr[i + 2], u3 = csr[i + 3];
        ushort4 v0 = *(const ushort4*)&Yb[(size_t)u0 * 256 + lane * 4];
        ushort4 v1 = *(const ushort4*)&Yb[(size_t)u1 * 256 + lane * 4];
        ushort4 v2 = *(const ushort4*)&Yb[(size_t)u2 * 256 + lane * 4];
        ushort4 v3 = *(const ushort4*)&Yb[(size_t)u3 * 256 + lane * 4];
        acc0.x += bf2f(v0.x) + bf2f(v1.x); acc1.x += bf2f(v2.x) + bf2f(v3.x);
        acc0.y += bf2f(v0.y) + bf2f(v1.y); acc1.y += bf2f(v2.y) + bf2f(v3.y);
        acc0.z += bf2f(v0.z) + bf2f(v1.z); acc1.z += bf2f(v2.z) + bf2f(v3.z);
        acc0.w += bf2f(v0.w) + bf2f(v1.w); acc1.w += bf2f(v2.w) + bf2f(v3.w);
    }
    for (; i < e; i++) {
        int u = csr[i];
        ushort4 v = *(const ushort4*)&Yb[(size_t)u * 256 + lane * 4];
        acc0.x += bf2f(v.x); acc0.y += bf2f(v.y); acc0.z += bf2f(v.z); acc0.w += bf2f(v.w);
    }
    float4 b = *(const float4*)&bias[lane * 4];
    ushort4 o;
    o.x = f2bf(fmaxf(acc0.x + acc1.x + b.x, 0.f));
    o.y = f2bf(fmaxf(acc0.y + acc1.y + b.y, 0.f));
    o.z = f2bf(fmaxf(acc0.z + acc1.z + b.z, 0.f));
    o.w = f2bf(fmaxf(acc0.w + acc1.w + b.w, 0.f));
    *(ushort4*)&out[(size_t)node * 256 + lane * 4] = o;
}

// ---------------- Aggregation over bf16 Z [N,128] -> mu/logvar fp32 (+bias) and bf16 zb [N,64] ----------------

__global__ __launch_bounds__(256) void agg_split_kernel(const unsigned short* __restrict__ Zb,
                                                        const int* __restrict__ offs,
                                                        const int* __restrict__ csr, const float* __restrict__ b2,
                                                        const float* __restrict__ b3, float* __restrict__ mu,
                                                        float* __restrict__ lv, unsigned short* __restrict__ zb) {
    int node = blockIdx.x * 4 + (threadIdx.x >> 6);
    int lane = threadIdx.x & 63;
    int s = offs[node], e = offs[node + 1];
    float2 acc0 = {0.f, 0.f}, acc1 = {0.f, 0.f};
    int i = s;
    for (; i + 3 < e; i += 4) {
        int u0 = csr[i], u1 = csr[i + 1], u2 = csr[i + 2], u3 = csr[i + 3];
        ushort2 v0 = *(const ushort2*)&Zb[(size_t)u0 * 128 + lane * 2];
        ushort2 v1 = *(const ushort2*)&Zb[(size_t)u1 * 128 + lane * 2];
        ushort2 v2 = *(const ushort2*)&Zb[(size_t)u2 * 128 + lane * 2];
        ushort2 v3 = *(const ushort2*)&Zb[(size_t)u3 * 128 + lane * 2];
        acc0.x += bf2f(v0.x) + bf2f(v1.x); acc1.x += bf2f(v2.x) + bf2f(v3.x);
        acc0.y += bf2f(v0.y) + bf2f(v1.y); acc1.y += bf2f(v2.y) + bf2f(v3.y);
    }
    for (; i < e; i++) {
        int u = csr[i];
        ushort2 v = *(const ushort2*)&Zb[(size_t)u * 128 + lane * 2];
        acc0.x += bf2f(v.x); acc0.y += bf2f(v.y);
    }
    float2 acc = {acc0.x + acc1.x, acc0.y + acc1.y};
    int col = lane * 2;
    if (col < 64) {
        acc.x += b2[col]; acc.y += b2[col + 1];
        *(float2*)&mu[(size_t)node * 64 + col] = acc;
        ushort2 q = {f2bf(acc.x), f2bf(acc.y)};
        *(ushort2*)&zb[(size_t)node * 64 + col] = q;
    } else {
        col -= 64;
        acc.x += b3[col]; acc.y += b3[col + 1];
        *(float2*)&lv[(size_t)node * 64 + col] = acc;
    }
}

// ---------------- adj = sigmoid(z z^T) via bf16 MFMA; zb = [8192, 64] bf16 ----------------
// Epilogue stages the 128x128 tile in LDS (padded) so global stores are
// 512 B-contiguous float4 runs per row (vs 64 B fragments from the raw C/D layout).

__global__ __launch_bounds__(256) void adj_mfma_kernel(const unsigned short* __restrict__ zb,
                                                       float* __restrict__ out) {
    __shared__ float tile[128][132];   // +4 pad: staging writes conflict-free
    const int tid = threadIdx.x;
    const int lane = tid & 63;
    const int wid = tid >> 6;
    const int waveM = wid >> 1, waveN = wid & 1;
    const int mb = waveM * 64, nb = waveN * 64;       // intra-block tile offset
    const int m_base = blockIdx.x * 128 + mb;
    const int n_base = blockIdx.y * 128 + nb;
    const int r = lane & 15;
    const int q = lane >> 4;

    short8v a[4][2], b[4][2];
#pragma unroll
    for (int i = 0; i < 4; i++)
#pragma unroll
        for (int s = 0; s < 2; s++) {
            a[i][s] = *(const short8v*)&zb[(size_t)(m_base + i * 16 + r) * 64 + s * 32 + q * 8];
            b[i][s] = *(const short8v*)&zb[(size_t)(n_base + i * 16 + r) * 64 + s * 32 + q * 8];
        }

    float4v acc[4][4] = {};
#pragma unroll
    for (int s = 0; s < 2; s++)
#pragma unroll
        for (int i = 0; i < 4; i++)
#pragma unroll
            for (int j = 0; j < 4; j++)
                acc[i][j] = __builtin_amdgcn_mfma_f32_16x16x32_bf16(a[i][s], b[j][s], acc[i][j], 0, 0, 0);

    // sigmoid + stage to LDS in C/D layout
#pragma unroll
    for (int i = 0; i < 4; i++)
#pragma unroll
        for (int j = 0; j < 4; j++) {
            int col = nb + j * 16 + r;
#pragma unroll
            for (int t = 0; t < 4; t++) {
                int row = mb + i * 16 + q * 4 + t;
                tile[row][col] = 1.0f / (1.0f + __expf(-acc[i][j][t]));
            }
        }
    __syncthreads();

    // coalesced write-out: each wave covers 2 rows/instr, 32 lanes x float4 = 512 B per row
    const int rhalf = lane >> 5;        // 0..1
    const int c4 = (lane & 31) * 4;     // col (floats)
    const size_t out_base = (size_t)(blockIdx.x * 128) * N_NODES + blockIdx.y * 128;
#pragma unroll
    for (int it = 0; it < 16; it++) {
        int row = it * 8 + wid * 2 + rhalf;
        float4 v = *(const float4*)&tile[row][c4];
        *(float4*)&out[out_base + (size_t)row * N_NODES + c4] = v;
    }
}

// ---------------- launch ----------------

extern "C" void kernel_launch(void* const* d_in, const int* in_sizes, int n_in,
                              void* d_out, int out_size, void* d_ws, size_t ws_size,
                              hipStream_t stream) {
    const float* X   = (const float*)d_in[0];
    const int*   src = (const int*)d_in[1];
    const int*   dst = (const int*)d_in[2];
    const float* W1  = (const float*)d_in[3];
    const float* b1  = (const float*)d_in[4];
    const float* W2  = (const float*)d_in[5];
    const float* b2  = (const float*)d_in[6];
    const float* W3  = (const float*)d_in[7];
    const float* b3  = (const float*)d_in[8];

    float* out    = (float*)d_out;
    float* adj    = out;                              // [8192*8192]
    float* mu_out = out + (size_t)N_NODES * N_NODES;  // [8192*64]
    float* lv_out = mu_out + (size_t)N_NODES * 64;    // [8192*64]

    // Workspace allocator: 1 KiB-aligned carve-outs (R2 lesson: no hand arithmetic).
    char* ws = (char*)d_ws;
    size_t off = 0;
    auto alloc = [&](size_t bytes) -> void* {
        void* p = ws + off;
        off += (bytes + 1023) & ~(size_t)1023;
        return p;
    };
    int* deg            = (int*)alloc(N_NODES * 4);
    int* cur            = (int*)alloc(N_NODES * 4);
    int* offs           = (int*)alloc((N_NODES + 1) * 4);
    int* csr            = (int*)alloc(N_EDGES * 4);
    unsigned short* Xb  = (unsigned short*)alloc((size_t)N_NODES * 512 * 2);
    unsigned short* W1b = (unsigned short*)alloc(256 * 512 * 2);
    unsigned short* W23b= (unsigned short*)alloc(128 * 256 * 2);
    unsigned short* Y1b = (unsigned short*)alloc((size_t)N_NODES * 256 * 2);
    unsigned short* Hb  = (unsigned short*)alloc((size_t)N_NODES * 256 * 2);
    unsigned short* Zb  = (unsigned short*)alloc((size_t)N_NODES * 128 * 2);
    unsigned short* zb  = (unsigned short*)alloc((size_t)N_NODES * 64 * 2);

    hipMemsetAsync(deg, 0, N_NODES * sizeof(int), stream);
    // hist (1024 blocks) + bf16 casts (4256 blocks) fused
    hist_prep_kernel<<<5280, 256, 0, stream>>>(dst, deg, X, W1, W2, W3, Xb, W1b, W23b);
    scan_kernel<<<1, 1024, 0, stream>>>(deg, offs, cur);           // also cur = offs
    scatter_kernel<<<N_EDGES / 256, 256, 0, stream>>>(src, dst, cur, csr);

    // Y1b = bf16(Xb @ W1b^T) : [8192,512]x[256,512]^T -> [8192,256]
    gemm_nt_mfma<2, 2, 4><<<dim3(256, 2), 256, 0, stream>>>(Xb, W1b, Y1b, 256, 512);
    // Hb = bf16(relu(agg(Y1b) + b1))
    agg_relu_kernel<<<N_NODES / 4, 256, 0, stream>>>(Y1b, offs, csr, b1, Hb);
    // Zb = bf16(Hb @ W23b^T) : [8192,256]x[128,256]^T -> [8192,128]
    gemm_nt_mfma<2, 1, 4><<<dim3(256, 2), 256, 0, stream>>>(Hb, W23b, Zb, 128, 256);
    // mu/logvar = agg(Zb) + b2/b3 (split); zb = bf16(mu)
    agg_split_kernel<<<N_NODES / 4, 256, 0, stream>>>(Zb, offs, csr, b2, b3, mu_out, lv_out, zb);
    // adj = sigmoid(zb @ zb^T) via MFMA, LDS-coalesced epilogue
    adj_mfma_kernel<<<dim3(64, 64), 256, 0, stream>>>(zb, adj);
}

// Round 7
// 375.521 us; speedup vs baseline: 1.1163x; 1.0359x over previous
//
#include <hip/hip_runtime.h>
#include <hip/hip_bf16.h>

#define N_NODES 8192
#define N_EDGES 262144

typedef __attribute__((ext_vector_type(8))) short short8v;
typedef __attribute__((ext_vector_type(4))) float float4v;

static __device__ __forceinline__ unsigned short f2bf(float f) {
    unsigned u = __float_as_uint(f);
    unsigned r = (u + 0x7FFF + ((u >> 16) & 1)) >> 16;   // RNE, finite values
    return (unsigned short)r;
}
static __device__ __forceinline__ float bf2f(unsigned short h) {
    return __uint_as_float(((unsigned)h) << 16);
}

// ---------------- fused: edge histogram + fp32->bf16 casts (independent, input-only) ----------------

__global__ __launch_bounds__(256) void hist_prep_kernel(const int* __restrict__ dst, int* __restrict__ deg,
                                                        const float* __restrict__ X, const float* __restrict__ W1,
                                                        const float* __restrict__ W2, const float* __restrict__ W3,
                                                        unsigned short* __restrict__ Xb,
                                                        unsigned short* __restrict__ W1b,
                                                        unsigned short* __restrict__ W23b) {
    int b = blockIdx.x;
    if (b < 1024) {
        int e = b * 256 + threadIdx.x;   // E == 1024*256 exactly
        atomicAdd(&deg[dst[e]], 1);
        return;
    }
    int i4 = ((b - 1024) * 256 + threadIdx.x) * 4;
    const float* srcp;
    unsigned short* dstp;
    int off;
    if (i4 < 4194304)      { srcp = X;  dstp = Xb;           off = i4; }
    else if (i4 < 4325376) { srcp = W1; dstp = W1b;          off = i4 - 4194304; }
    else if (i4 < 4341760) { srcp = W2; dstp = W23b;         off = i4 - 4325376; }
    else                   { srcp = W3; dstp = W23b + 16384; off = i4 - 4341760; }
    float4 v = *(const float4*)&srcp[off];
    ushort4 o = {f2bf(v.x), f2bf(v.y), f2bf(v.z), f2bf(v.w)};
    *(ushort4*)&dstp[off] = o;
}

// ---------------- exclusive scan; also initializes cur = offs for the scatter ----------------

__global__ __launch_bounds__(1024) void scan_kernel(const int* __restrict__ deg, int* __restrict__ offs,
                                                    int* __restrict__ cur) {
    __shared__ int sums[1024];
    int t = threadIdx.x;
    int v[8];
    int s = 0;
#pragma unroll
    for (int i = 0; i < 8; i++) { v[i] = deg[t * 8 + i]; s += v[i]; }
    sums[t] = s;
    __syncthreads();
    for (int off = 1; off < 1024; off <<= 1) {
        int x = (t >= off) ? sums[t - off] : 0;
        __syncthreads();
        sums[t] += x;
        __syncthreads();
    }
    int ex = (t == 0) ? 0 : sums[t - 1];
#pragma unroll
    for (int i = 0; i < 8; i++) { offs[t * 8 + i] = ex; cur[t * 8 + i] = ex; ex += v[i]; }
    if (t == 1023) offs[N_NODES] = ex;
}

__global__ __launch_bounds__(256) void scatter_kernel(const int* __restrict__ src, const int* __restrict__ dst,
                                                      int* __restrict__ cur, int* __restrict__ csr) {
    int e = blockIdx.x * 256 + threadIdx.x;
    int d = dst[e];
    int p = atomicAdd(&cur[d], 1);
    csr[p] = src[e];
}

// ---------------- MFMA GEMM: C[M,N] = A[M,K] @ B[N,K]^T, all row-major bf16 ----------------
// Direct global fragment loads: A[m=lane&15][k=(lane>>4)*8+j]; C/D: col=lane&15, row=(lane>>4)*4+reg.
// K-loop software-pipelined: next iteration's fragments prefetched before current MFMAs.

template <int MI, int NJ, int WN>
__global__ __launch_bounds__(256) void gemm_nt_mfma(const unsigned short* __restrict__ A,
                                                    const unsigned short* __restrict__ B,
                                                    unsigned short* __restrict__ C,
                                                    int N, int K) {
    constexpr int MW = 4 / WN;
    const int tid = threadIdx.x;
    const int lane = tid & 63;
    const int w = tid >> 6;
    const int r = lane & 15, q = lane >> 4;
    const int m0 = blockIdx.x * (MI * 16 * MW) + (w / WN) * (MI * 16);
    const int n0 = blockIdx.y * (NJ * 16 * WN) + (w % WN) * (NJ * 16);
    const unsigned short* Ap = &A[q * 8];
    const unsigned short* Bp = &B[q * 8];
    float4v acc[MI][NJ] = {};
    short8v a[MI], b[NJ], an[MI], bn[NJ];
#pragma unroll
    for (int i = 0; i < MI; i++) a[i] = *(const short8v*)&Ap[(size_t)(m0 + i * 16 + r) * K];
#pragma unroll
    for (int j = 0; j < NJ; j++) b[j] = *(const short8v*)&Bp[(size_t)(n0 + j * 16 + r) * K];
    for (int k = 32; k < K; k += 32) {
#pragma unroll
        for (int i = 0; i < MI; i++) an[i] = *(const short8v*)&Ap[(size_t)(m0 + i * 16 + r) * K + k];
#pragma unroll
        for (int j = 0; j < NJ; j++) bn[j] = *(const short8v*)&Bp[(size_t)(n0 + j * 16 + r) * K + k];
#pragma unroll
        for (int i = 0; i < MI; i++)
#pragma unroll
            for (int j = 0; j < NJ; j++)
                acc[i][j] = __builtin_amdgcn_mfma_f32_16x16x32_bf16(a[i], b[j], acc[i][j], 0, 0, 0);
#pragma unroll
        for (int i = 0; i < MI; i++) a[i] = an[i];
#pragma unroll
        for (int j = 0; j < NJ; j++) b[j] = bn[j];
    }
#pragma unroll
    for (int i = 0; i < MI; i++)
#pragma unroll
        for (int j = 0; j < NJ; j++)
            acc[i][j] = __builtin_amdgcn_mfma_f32_16x16x32_bf16(a[i], b[j], acc[i][j], 0, 0, 0);
#pragma unroll
    for (int i = 0; i < MI; i++)
#pragma unroll
        for (int j = 0; j < NJ; j++) {
            int col = n0 + j * 16 + r;
#pragma unroll
            for (int t = 0; t < 4; t++) {
                int row = m0 + i * 16 + q * 4 + t;
                C[(size_t)row * N + col] = f2bf(acc[i][j][t]);
            }
        }
}

// ---------------- Aggregation (CSR gather-sum) over bf16 Y1 [N,256], + bias + relu -> bf16 hidden ----------------

__global__ __launch_bounds__(256) void agg_relu_kernel(const unsigned short* __restrict__ Yb,
                                                       const int* __restrict__ offs,
                                                       const int* __restrict__ csr, const float* __restrict__ bias,
                                                       unsigned short* __restrict__ out) {
    int node = blockIdx.x * 4 + (threadIdx.x >> 6);
    int lane = threadIdx.x & 63;
    int s = offs[node], e = offs[node + 1];
    float4 acc0 = {0.f, 0.f, 0.f, 0.f}, acc1 = {0.f, 0.f, 0.f, 0.f};
    int i = s;
    for (; i + 3 < e; i += 4) {
        int u0 = csr[i], u1 = csr[i + 1], u2 = csr[i + 2], u3 = csr[i + 3];
        ushort4 v0 = *(const ushort4*)&Yb[(size_t)u0 * 256 + lane * 4];
        ushort4 v1 = *(const ushort4*)&Yb[(size_t)u1 * 256 + lane * 4];
        ushort4 v2 = *(const ushort4*)&Yb[(size_t)u2 * 256 + lane * 4];
        ushort4 v3 = *(const ushort4*)&Yb[(size_t)u3 * 256 + lane * 4];
        acc0.x += bf2f(v0.x) + bf2f(v1.x); acc1.x += bf2f(v2.x) + bf2f(v3.x);
        acc0.y += bf2f(v0.y) + bf2f(v1.y); acc1.y += bf2f(v2.y) + bf2f(v3.y);
        acc0.z += bf2f(v0.z) + bf2f(v1.z); acc1.z += bf2f(v2.z) + bf2f(v3.z);
        acc0.w += bf2f(v0.w) + bf2f(v1.w); acc1.w += bf2f(v2.w) + bf2f(v3.w);
    }
    for (; i < e; i++) {
        int u = csr[i];
        ushort4 v = *(const ushort4*)&Yb[(size_t)u * 256 + lane * 4];
        acc0.x += bf2f(v.x); acc0.y += bf2f(v.y); acc0.z += bf2f(v.z); acc0.w += bf2f(v.w);
    }
    float4 b = *(const float4*)&bias[lane * 4];
    ushort4 o;
    o.x = f2bf(fmaxf(acc0.x + acc1.x + b.x, 0.f));
    o.y = f2bf(fmaxf(acc0.y + acc1.y + b.y, 0.f));
    o.z = f2bf(fmaxf(acc0.z + acc1.z + b.z, 0.f));
    o.w = f2bf(fmaxf(acc0.w + acc1.w + b.w, 0.f));
    *(ushort4*)&out[(size_t)node * 256 + lane * 4] = o;
}

// ---------------- Aggregation over bf16 Z [N,128] -> mu/logvar fp32 (+bias) and bf16 zb [N,64] ----------------

__global__ __launch_bounds__(256) void agg_split_kernel(const unsigned short* __restrict__ Zb,
                                                        const int* __restrict__ offs,
                                                        const int* __restrict__ csr, const float* __restrict__ b2,
                                                        const float* __restrict__ b3, float* __restrict__ mu,
                                                        float* __restrict__ lv, unsigned short* __restrict__ zb) {
    int node = blockIdx.x * 4 + (threadIdx.x >> 6);
    int lane = threadIdx.x & 63;
    int s = offs[node], e = offs[node + 1];
    float2 acc0 = {0.f, 0.f}, acc1 = {0.f, 0.f};
    int i = s;
    for (; i + 3 < e; i += 4) {
        int u0 = csr[i], u1 = csr[i + 1], u2 = csr[i + 2], u3 = csr[i + 3];
        ushort2 v0 = *(const ushort2*)&Zb[(size_t)u0 * 128 + lane * 2];
        ushort2 v1 = *(const ushort2*)&Zb[(size_t)u1 * 128 + lane * 2];
        ushort2 v2 = *(const ushort2*)&Zb[(size_t)u2 * 128 + lane * 2];
        ushort2 v3 = *(const ushort2*)&Zb[(size_t)u3 * 128 + lane * 2];
        acc0.x += bf2f(v0.x) + bf2f(v1.x); acc1.x += bf2f(v2.x) + bf2f(v3.x);
        acc0.y += bf2f(v0.y) + bf2f(v1.y); acc1.y += bf2f(v2.y) + bf2f(v3.y);
    }
    for (; i < e; i++) {
        int u = csr[i];
        ushort2 v = *(const ushort2*)&Zb[(size_t)u * 128 + lane * 2];
        acc0.x += bf2f(v.x); acc0.y += bf2f(v.y);
    }
    float2 acc = {acc0.x + acc1.x, acc0.y + acc1.y};
    int col = lane * 2;
    if (col < 64) {
        acc.x += b2[col]; acc.y += b2[col + 1];
        *(float2*)&mu[(size_t)node * 64 + col] = acc;
        ushort2 q = {f2bf(acc.x), f2bf(acc.y)};
        *(ushort2*)&zb[(size_t)node * 64 + col] = q;
    } else {
        col -= 64;
        acc.x += b3[col]; acc.y += b3[col + 1];
        *(float2*)&lv[(size_t)node * 64 + col] = acc;
    }
}

// ---------------- adj = sigmoid(z z^T) via bf16 MFMA; zb = [8192, 64] bf16 ----------------
// Direct C/D-layout stores (R4-proven; LDS-staged epilogue measured +5.5 us, nt stores +36 us).

__global__ __launch_bounds__(256) void adj_mfma_kernel(const unsigned short* __restrict__ zb,
                                                       float* __restrict__ out) {
    const int tid = threadIdx.x;
    const int lane = tid & 63;
    const int wid = tid >> 6;
    const int waveM = wid >> 1, waveN = wid & 1;
    const int m_base = blockIdx.x * 128 + waveM * 64;
    const int n_base = blockIdx.y * 128 + waveN * 64;
    const int r = lane & 15;
    const int q = lane >> 4;

    short8v a[4][2], b[4][2];
#pragma unroll
    for (int i = 0; i < 4; i++)
#pragma unroll
        for (int s = 0; s < 2; s++) {
            a[i][s] = *(const short8v*)&zb[(size_t)(m_base + i * 16 + r) * 64 + s * 32 + q * 8];
            b[i][s] = *(const short8v*)&zb[(size_t)(n_base + i * 16 + r) * 64 + s * 32 + q * 8];
        }

    float4v acc[4][4] = {};
#pragma unroll
    for (int s = 0; s < 2; s++)
#pragma unroll
        for (int i = 0; i < 4; i++)
#pragma unroll
            for (int j = 0; j < 4; j++)
                acc[i][j] = __builtin_amdgcn_mfma_f32_16x16x32_bf16(a[i][s], b[j][s], acc[i][j], 0, 0, 0);

#pragma unroll
    for (int i = 0; i < 4; i++)
#pragma unroll
        for (int j = 0; j < 4; j++) {
            int col = n_base + j * 16 + r;
#pragma unroll
            for (int t = 0; t < 4; t++) {
                int row = m_base + i * 16 + q * 4 + t;
                float v = 1.0f / (1.0f + __expf(-acc[i][j][t]));
                out[(size_t)row * N_NODES + col] = v;
            }
        }
}

// ---------------- launch ----------------

extern "C" void kernel_launch(void* const* d_in, const int* in_sizes, int n_in,
                              void* d_out, int out_size, void* d_ws, size_t ws_size,
                              hipStream_t stream) {
    const float* X   = (const float*)d_in[0];
    const int*   src = (const int*)d_in[1];
    const int*   dst = (const int*)d_in[2];
    const float* W1  = (const float*)d_in[3];
    const float* b1  = (const float*)d_in[4];
    const float* W2  = (const float*)d_in[5];
    const float* b2  = (const float*)d_in[6];
    const float* W3  = (const float*)d_in[7];
    const float* b3  = (const float*)d_in[8];

    float* out    = (float*)d_out;
    float* adj    = out;                              // [8192*8192]
    float* mu_out = out + (size_t)N_NODES * N_NODES;  // [8192*64]
    float* lv_out = mu_out + (size_t)N_NODES * 64;    // [8192*64]

    // Workspace allocator: 1 KiB-aligned carve-outs (R2 lesson: no hand arithmetic).
    char* ws = (char*)d_ws;
    size_t off = 0;
    auto alloc = [&](size_t bytes) -> void* {
        void* p = ws + off;
        off += (bytes + 1023) & ~(size_t)1023;
        return p;
    };
    int* deg            = (int*)alloc(N_NODES * 4);
    int* cur            = (int*)alloc(N_NODES * 4);
    int* offs           = (int*)alloc((N_NODES + 1) * 4);
    int* csr            = (int*)alloc(N_EDGES * 4);
    unsigned short* Xb  = (unsigned short*)alloc((size_t)N_NODES * 512 * 2);
    unsigned short* W1b = (unsigned short*)alloc(256 * 512 * 2);
    unsigned short* W23b= (unsigned short*)alloc(128 * 256 * 2);
    unsigned short* Y1b = (unsigned short*)alloc((size_t)N_NODES * 256 * 2);
    unsigned short* Hb  = (unsigned short*)alloc((size_t)N_NODES * 256 * 2);
    unsigned short* Zb  = (unsigned short*)alloc((size_t)N_NODES * 128 * 2);
    unsigned short* zb  = (unsigned short*)alloc((size_t)N_NODES * 64 * 2);

    hipMemsetAsync(deg, 0, N_NODES * sizeof(int), stream);
    // hist (1024 blocks) + bf16 casts (4256 blocks) fused
    hist_prep_kernel<<<5280, 256, 0, stream>>>(dst, deg, X, W1, W2, W3, Xb, W1b, W23b);
    scan_kernel<<<1, 1024, 0, stream>>>(deg, offs, cur);           // also cur = offs
    scatter_kernel<<<N_EDGES / 256, 256, 0, stream>>>(src, dst, cur, csr);

    // Y1b = bf16(Xb @ W1b^T) : [8192,512]x[256,512]^T -> [8192,256]
    gemm_nt_mfma<2, 2, 4><<<dim3(256, 2), 256, 0, stream>>>(Xb, W1b, Y1b, 256, 512);
    // Hb = bf16(relu(agg(Y1b) + b1))
    agg_relu_kernel<<<N_NODES / 4, 256, 0, stream>>>(Y1b, offs, csr, b1, Hb);
    // Zb = bf16(Hb @ W23b^T) : [8192,256]x[128,256]^T -> [8192,128]
    gemm_nt_mfma<2, 1, 4><<<dim3(256, 2), 256, 0, stream>>>(Hb, W23b, Zb, 128, 256);
    // mu/logvar = agg(Zb) + b2/b3 (split); zb = bf16(mu)
    agg_split_kernel<<<N_NODES / 4, 256, 0, stream>>>(Zb, offs, csr, b2, b3, mu_out, lv_out, zb);
    // adj = sigmoid(zb @ zb^T) via MFMA, direct stores
    adj_mfma_kernel<<<dim3(64, 64), 256, 0, stream>>>(zb, adj);
}